// Round 15
// baseline (458.903 us; speedup 1.0000x reference)
//
#include <hip/hip_runtime.h>

#define NN    4096
#define BB    4
#define INDIM 64
#define HD    256
#define KMAX  32
#define SLOTS 33   // K neighbors + self

// ---------------------------------------------------------------------------
// Kernel 1: XL = x@Wl + bl, XR = x@Wr + br   ([16384,64] @ [64,256])
// R12: wave <-> node, lane <-> 4 features. W loads vectorized to float4
// (1KB/wave-inst, was 4B/lane scalar x128 — Guideline 13); x row is
// wave-uniform broadcast; float4 stores. 4 nodes/block.
// ---------------------------------------------------------------------------
__global__ __launch_bounds__(256, 4) void xlr_kernel(
    const float* __restrict__ x,
    const float* __restrict__ Wl, const float* __restrict__ bl,
    const float* __restrict__ Wr, const float* __restrict__ br,
    float* __restrict__ XL, float* __restrict__ XR)
{
    const int t = threadIdx.x;
    const int w = t >> 6;                 // wave = node within block
    const int l = t & 63;                 // lane = feature group 4l..4l+3
    const int node = blockIdx.x * 4 + w;
    const float* xrow = x + (size_t)node * INDIM;

    float4 accl = make_float4(0.f, 0.f, 0.f, 0.f);
    float4 accr = make_float4(0.f, 0.f, 0.f, 0.f);

    #pragma unroll 8
    for (int c = 0; c < INDIM; ++c) {
        float  xc  = xrow[c];                                  // uniform bcast
        float4 wl4 = *(const float4*)(Wl + c * HD + 4 * l);    // coalesced 16B
        float4 wr4 = *(const float4*)(Wr + c * HD + 4 * l);
        accl.x = fmaf(xc, wl4.x, accl.x);
        accl.y = fmaf(xc, wl4.y, accl.y);
        accl.z = fmaf(xc, wl4.z, accl.z);
        accl.w = fmaf(xc, wl4.w, accl.w);
        accr.x = fmaf(xc, wr4.x, accr.x);
        accr.y = fmaf(xc, wr4.y, accr.y);
        accr.z = fmaf(xc, wr4.z, accr.z);
        accr.w = fmaf(xc, wr4.w, accr.w);
    }
    float4 bl4 = *(const float4*)(bl + 4 * l);
    float4 br4 = *(const float4*)(br + 4 * l);
    accl.x += bl4.x; accl.y += bl4.y; accl.z += bl4.z; accl.w += bl4.w;
    accr.x += br4.x; accr.y += br4.y; accr.z += br4.z; accr.w += br4.w;
    *(float4*)(XL + (size_t)node * HD + 4 * l) = accl;
    *(float4*)(XR + (size_t)node * HD + 4 * l) = accr;
}

// ---------------------------------------------------------------------------
// Kernel 2: fused GATv2 + bias + LayerNorm, one block per node.
// R12: online pass fully unrolled to 9 predicated steps with NAMED q0..q8
// (no array -> no R8-style spill; loads unconditional via clamped index)
// so all 9 gathers are in flight before the serial (m,s,acc) chain.
// Invalid slots: p=0, state unchanged. Was: runtime-bound loop = 1 load
// in flight (latency-serialized; R12 gat ~130us vs 43us adj floor).
// ---------------------------------------------------------------------------
__global__ __launch_bounds__(256, 4) void gat_kernel(
    const float* __restrict__ adj,
    const float* __restrict__ XL, const float* __restrict__ XR,
    const float* __restrict__ att, const float* __restrict__ bias,
    const float* __restrict__ gamma, const float* __restrict__ beta,
    float* __restrict__ out)
{
    const int node = blockIdx.x;          // b*N + i
    const int b    = node >> 12;          // N = 4096
    const int i    = node & (NN - 1);
    const int t    = threadIdx.x;
    const int w    = t >> 6;              // wave id
    const int l    = t & 63;              // lane

    __shared__ int   s_nbr[SLOTS];
    __shared__ int   s_cnt;
    __shared__ float s_acc[4][HD];        // per-wave weighted sums (feature-major)
    __shared__ float s_m[4][64];          // per-wave running max
    __shared__ float s_s[4][64];          // per-wave running denom
    __shared__ float s_red[4];

    const float4 xr4  = *(const float4*)(XR + (size_t)node * HD + 4 * l);
    const float4 att4 = *(const float4*)(att + 4 * l);
    const float biasv = bias[t];
    const float gv    = gamma[t];
    const float bv    = beta[t];

    // ---- Phase A: scan adjacency row (16 KB), compact nonzero columns ----
    const float4* row = (const float4*)(adj + (size_t)node * NN);
    float4 v[4];
    #pragma unroll
    for (int r = 0; r < 4; ++r) v[r] = row[r * 256 + t];

    if (t == 0) s_cnt = 0;
    __syncthreads();

    #pragma unroll
    for (int r = 0; r < 4; ++r) {
        int j0 = (r * 256 + t) * 4;
        if (v[r].x > 0.f) { int p = atomicAdd(&s_cnt, 1); if (p < KMAX) s_nbr[p] = j0;     }
        if (v[r].y > 0.f) { int p = atomicAdd(&s_cnt, 1); if (p < KMAX) s_nbr[p] = j0 + 1; }
        if (v[r].z > 0.f) { int p = atomicAdd(&s_cnt, 1); if (p < KMAX) s_nbr[p] = j0 + 2; }
        if (v[r].w > 0.f) { int p = atomicAdd(&s_cnt, 1); if (p < KMAX) s_nbr[p] = j0 + 3; }
    }
    __syncthreads();
    int cnt = s_cnt; if (cnt > KMAX) cnt = KMAX;
    if (t >= cnt && t < SLOTS) s_nbr[t] = i;      // self-loop at slot cnt
    __syncthreads();
    const int total = cnt + 1;                    // valid slots 0..cnt

    const size_t bbase = (size_t)b * NN * HD;
    const int kt = total - 1;                     // clamp for safe loads

    // ---- issue ALL 9 gathers up front (named regs, unconditional) ----
    const float* XB = XL + bbase;
    int j0 = s_nbr[min(w,      kt)];
    int j1 = s_nbr[min(w +  4, kt)];
    int j2 = s_nbr[min(w +  8, kt)];
    int j3 = s_nbr[min(w + 12, kt)];
    int j4 = s_nbr[min(w + 16, kt)];
    int j5 = s_nbr[min(w + 20, kt)];
    int j6 = s_nbr[min(w + 24, kt)];
    int j7 = s_nbr[min(w + 28, kt)];
    int j8 = s_nbr[min(w + 32, kt)];
    float4 q0 = *(const float4*)(XB + (size_t)j0 * HD + 4 * l);
    float4 q1 = *(const float4*)(XB + (size_t)j1 * HD + 4 * l);
    float4 q2 = *(const float4*)(XB + (size_t)j2 * HD + 4 * l);
    float4 q3 = *(const float4*)(XB + (size_t)j3 * HD + 4 * l);
    float4 q4 = *(const float4*)(XB + (size_t)j4 * HD + 4 * l);
    float4 q5 = *(const float4*)(XB + (size_t)j5 * HD + 4 * l);
    float4 q6 = *(const float4*)(XB + (size_t)j6 * HD + 4 * l);
    float4 q7 = *(const float4*)(XB + (size_t)j7 * HD + 4 * l);
    float4 q8 = *(const float4*)(XB + (size_t)j8 * HD + 4 * l);

    // ---- online softmax+aggregate chain (9 predicated steps) ----
    float m = -3.0e38f, s = 0.f;
    float a0 = 0.f, a1 = 0.f, a2 = 0.f, a3 = 0.f;

#define ONLINE(Q, K)                                                        \
    do {                                                                    \
        const bool val = (K) < total;                                       \
        float s0 = Q.x + xr4.x; s0 = fmaxf(s0, 0.f) + 0.2f * fminf(s0, 0.f);\
        float s1 = Q.y + xr4.y; s1 = fmaxf(s1, 0.f) + 0.2f * fminf(s1, 0.f);\
        float s2 = Q.z + xr4.z; s2 = fmaxf(s2, 0.f) + 0.2f * fminf(s2, 0.f);\
        float s3 = Q.w + xr4.w; s3 = fmaxf(s3, 0.f) + 0.2f * fminf(s3, 0.f);\
        float c = att4.x * s0;                                              \
        c = fmaf(att4.y, s1, c);                                            \
        c = fmaf(att4.z, s2, c);                                            \
        c = fmaf(att4.w, s3, c);                                            \
        c += __shfl_xor(c, 1);                                              \
        c += __shfl_xor(c, 2);                                              \
        c += __shfl_xor(c, 4);                                              \
        c += __shfl_xor(c, 8);                                              \
        float mn = val ? fmaxf(m, c) : m;                                   \
        float p  = val ? __expf(c - mn) : 0.f;                              \
        float sc = __expf(m - mn);                                          \
        s  = fmaf(s, sc, p);                                                \
        a0 = fmaf(p, Q.x, a0 * sc);                                         \
        a1 = fmaf(p, Q.y, a1 * sc);                                         \
        a2 = fmaf(p, Q.z, a2 * sc);                                         \
        a3 = fmaf(p, Q.w, a3 * sc);                                         \
        m  = mn;                                                            \
    } while (0)

    ONLINE(q0, w);
    ONLINE(q1, w + 4);
    ONLINE(q2, w + 8);
    ONLINE(q3, w + 12);
    ONLINE(q4, w + 16);
    ONLINE(q5, w + 20);
    ONLINE(q6, w + 24);
    ONLINE(q7, w + 28);
    ONLINE(q8, w + 32);
#undef ONLINE

    // publish per-wave state
    *(float4*)&s_acc[w][4 * l] = make_float4(a0, a1, a2, a3);
    s_m[w][l] = m;
    s_s[w][l] = s;
    __syncthreads();

    // ---- merge 4 waves (thread t <-> feature t; holder lane g = t/4) ----
    const int g = t >> 2;
    float m0 = s_m[0][g], m1 = s_m[1][g], m2 = s_m[2][g], m3 = s_m[3][g];
    float M  = fmaxf(fmaxf(m0, m1), fmaxf(m2, m3));
    float w0 = __expf(m0 - M), w1 = __expf(m1 - M);
    float w2 = __expf(m2 - M), w3 = __expf(m3 - M);
    float den = w0 * s_s[0][g] + w1 * s_s[1][g] + w2 * s_s[2][g] + w3 * s_s[3][g];
    float num = w0 * s_acc[0][t] + w1 * s_acc[1][t] + w2 * s_acc[2][t] + w3 * s_acc[3][t];
    float acc = num / den + biasv;

    // ---- LayerNorm over 256 features (two-pass, block reduce) ----
    float ssum = acc;
    #pragma unroll
    for (int off = 32; off; off >>= 1) ssum += __shfl_xor(ssum, off);
    if (l == 0) s_red[w] = ssum;
    __syncthreads();
    float mu = (s_red[0] + s_red[1] + s_red[2] + s_red[3]) * (1.f / 256.f);
    __syncthreads();
    float d  = acc - mu;
    float dv = d * d;
    #pragma unroll
    for (int off = 32; off; off >>= 1) dv += __shfl_xor(dv, off);
    if (l == 0) s_red[w] = dv;
    __syncthreads();
    float var  = (s_red[0] + s_red[1] + s_red[2] + s_red[3]) * (1.f / 256.f);
    float rstd = rsqrtf(var + 1e-5f);
    out[(size_t)node * HD + t] = d * rstd * gv + bv;
}

// ---------------------------------------------------------------------------
extern "C" void kernel_launch(void* const* d_in, const int* in_sizes, int n_in,
                              void* d_out, int out_size, void* d_ws, size_t ws_size,
                              hipStream_t stream)
{
    const float* x     = (const float*)d_in[0];
    const float* adj   = (const float*)d_in[1];
    const float* Wl    = (const float*)d_in[2];
    const float* bl    = (const float*)d_in[3];
    const float* Wr    = (const float*)d_in[4];
    const float* br    = (const float*)d_in[5];
    const float* att   = (const float*)d_in[6];
    const float* bias  = (const float*)d_in[7];
    const float* gamma = (const float*)d_in[8];
    const float* beta  = (const float*)d_in[9];
    float* out = (float*)d_out;

    float* XL = (float*)d_ws;                       // 16 MiB
    float* XR = XL + (size_t)BB * NN * HD;          // 16 MiB

    xlr_kernel<<<BB * NN / 4, 256, 0, stream>>>(x, Wl, bl, Wr, br, XL, XR);
    gat_kernel<<<BB * NN, 256, 0, stream>>>(adj, XL, XR, att, bias, gamma, beta, out);
}

// Round 16
// 406.021 us; speedup vs baseline: 1.1302x; 1.1302x over previous
//
#include <hip/hip_runtime.h>

#define NN    4096
#define BB    4
#define INDIM 64
#define HD    256
#define KMAX  32
#define SLOTS 33   // K neighbors + self

// ---------------------------------------------------------------------------
// Kernel 1: XL = x@Wl + bl, XR = x@Wr + br   ([16384,64] @ [64,256])
// R15-AB: EXACT R10 version (measured inside the 419us run). t <-> feature,
// 4 nodes/block, W rows shared block-wide via L1 (128KB/block, not /wave —
// R12's wave<->node variant quadrupled W re-reads, suspected +40us).
// ---------------------------------------------------------------------------
__global__ __launch_bounds__(256, 4) void xlr_kernel(
    const float* __restrict__ x,
    const float* __restrict__ Wl, const float* __restrict__ bl,
    const float* __restrict__ Wr, const float* __restrict__ br,
    float* __restrict__ XL, float* __restrict__ XR)
{
    const int t = threadIdx.x;            // output feature 0..255
    const int base = blockIdx.x * 4;      // 4 nodes per block
    const float* xp = x + (size_t)base * INDIM;

    float al0=0.f, al1=0.f, al2=0.f, al3=0.f;
    float ar0=0.f, ar1=0.f, ar2=0.f, ar3=0.f;

    #pragma unroll 8
    for (int c = 0; c < INDIM; ++c) {
        float wl = Wl[c * HD + t];
        float wr = Wr[c * HD + t];
        float x0 = xp[c];                 // uniform -> broadcast
        float x1 = xp[INDIM + c];
        float x2 = xp[2 * INDIM + c];
        float x3 = xp[3 * INDIM + c];
        al0 = fmaf(x0, wl, al0); ar0 = fmaf(x0, wr, ar0);
        al1 = fmaf(x1, wl, al1); ar1 = fmaf(x1, wr, ar1);
        al2 = fmaf(x2, wl, al2); ar2 = fmaf(x2, wr, ar2);
        al3 = fmaf(x3, wl, al3); ar3 = fmaf(x3, wr, ar3);
    }
    const float blv = bl[t], brv = br[t];
    XL[(size_t)(base + 0) * HD + t] = al0 + blv;
    XL[(size_t)(base + 1) * HD + t] = al1 + blv;
    XL[(size_t)(base + 2) * HD + t] = al2 + blv;
    XL[(size_t)(base + 3) * HD + t] = al3 + blv;
    XR[(size_t)(base + 0) * HD + t] = ar0 + brv;
    XR[(size_t)(base + 1) * HD + t] = ar1 + brv;
    XR[(size_t)(base + 2) * HD + t] = ar2 + brv;
    XR[(size_t)(base + 3) * HD + t] = ar3 + brv;
}

// ---------------------------------------------------------------------------
// Kernel 2: fused GATv2 + bias + LayerNorm, one block per node.
// R15-AB: EXACT R12/R15 version kept (unrolled 9 named gathers). Under test
// vs the R10 runtime-loop version via total-time attribution.
// ---------------------------------------------------------------------------
__global__ __launch_bounds__(256, 4) void gat_kernel(
    const float* __restrict__ adj,
    const float* __restrict__ XL, const float* __restrict__ XR,
    const float* __restrict__ att, const float* __restrict__ bias,
    const float* __restrict__ gamma, const float* __restrict__ beta,
    float* __restrict__ out)
{
    const int node = blockIdx.x;          // b*N + i
    const int b    = node >> 12;          // N = 4096
    const int i    = node & (NN - 1);
    const int t    = threadIdx.x;
    const int w    = t >> 6;              // wave id
    const int l    = t & 63;              // lane

    __shared__ int   s_nbr[SLOTS];
    __shared__ int   s_cnt;
    __shared__ float s_acc[4][HD];        // per-wave weighted sums (feature-major)
    __shared__ float s_m[4][64];          // per-wave running max
    __shared__ float s_s[4][64];          // per-wave running denom
    __shared__ float s_red[4];

    const float4 xr4  = *(const float4*)(XR + (size_t)node * HD + 4 * l);
    const float4 att4 = *(const float4*)(att + 4 * l);
    const float biasv = bias[t];
    const float gv    = gamma[t];
    const float bv    = beta[t];

    // ---- Phase A: scan adjacency row (16 KB), compact nonzero columns ----
    const float4* row = (const float4*)(adj + (size_t)node * NN);
    float4 v[4];
    #pragma unroll
    for (int r = 0; r < 4; ++r) v[r] = row[r * 256 + t];

    if (t == 0) s_cnt = 0;
    __syncthreads();

    #pragma unroll
    for (int r = 0; r < 4; ++r) {
        int j0 = (r * 256 + t) * 4;
        if (v[r].x > 0.f) { int p = atomicAdd(&s_cnt, 1); if (p < KMAX) s_nbr[p] = j0;     }
        if (v[r].y > 0.f) { int p = atomicAdd(&s_cnt, 1); if (p < KMAX) s_nbr[p] = j0 + 1; }
        if (v[r].z > 0.f) { int p = atomicAdd(&s_cnt, 1); if (p < KMAX) s_nbr[p] = j0 + 2; }
        if (v[r].w > 0.f) { int p = atomicAdd(&s_cnt, 1); if (p < KMAX) s_nbr[p] = j0 + 3; }
    }
    __syncthreads();
    int cnt = s_cnt; if (cnt > KMAX) cnt = KMAX;
    if (t >= cnt && t < SLOTS) s_nbr[t] = i;      // self-loop at slot cnt
    __syncthreads();
    const int total = cnt + 1;                    // valid slots 0..cnt

    const size_t bbase = (size_t)b * NN * HD;
    const int kt = total - 1;                     // clamp for safe loads

    // ---- issue ALL 9 gathers up front (named regs, unconditional) ----
    const float* XB = XL + bbase;
    int j0 = s_nbr[min(w,      kt)];
    int j1 = s_nbr[min(w +  4, kt)];
    int j2 = s_nbr[min(w +  8, kt)];
    int j3 = s_nbr[min(w + 12, kt)];
    int j4 = s_nbr[min(w + 16, kt)];
    int j5 = s_nbr[min(w + 20, kt)];
    int j6 = s_nbr[min(w + 24, kt)];
    int j7 = s_nbr[min(w + 28, kt)];
    int j8 = s_nbr[min(w + 32, kt)];
    float4 q0 = *(const float4*)(XB + (size_t)j0 * HD + 4 * l);
    float4 q1 = *(const float4*)(XB + (size_t)j1 * HD + 4 * l);
    float4 q2 = *(const float4*)(XB + (size_t)j2 * HD + 4 * l);
    float4 q3 = *(const float4*)(XB + (size_t)j3 * HD + 4 * l);
    float4 q4 = *(const float4*)(XB + (size_t)j4 * HD + 4 * l);
    float4 q5 = *(const float4*)(XB + (size_t)j5 * HD + 4 * l);
    float4 q6 = *(const float4*)(XB + (size_t)j6 * HD + 4 * l);
    float4 q7 = *(const float4*)(XB + (size_t)j7 * HD + 4 * l);
    float4 q8 = *(const float4*)(XB + (size_t)j8 * HD + 4 * l);

    // ---- online softmax+aggregate chain (9 predicated steps) ----
    float m = -3.0e38f, s = 0.f;
    float a0 = 0.f, a1 = 0.f, a2 = 0.f, a3 = 0.f;

#define ONLINE(Q, K)                                                        \
    do {                                                                    \
        const bool val = (K) < total;                                       \
        float s0 = Q.x + xr4.x; s0 = fmaxf(s0, 0.f) + 0.2f * fminf(s0, 0.f);\
        float s1 = Q.y + xr4.y; s1 = fmaxf(s1, 0.f) + 0.2f * fminf(s1, 0.f);\
        float s2 = Q.z + xr4.z; s2 = fmaxf(s2, 0.f) + 0.2f * fminf(s2, 0.f);\
        float s3 = Q.w + xr4.w; s3 = fmaxf(s3, 0.f) + 0.2f * fminf(s3, 0.f);\
        float c = att4.x * s0;                                              \
        c = fmaf(att4.y, s1, c);                                            \
        c = fmaf(att4.z, s2, c);                                            \
        c = fmaf(att4.w, s3, c);                                            \
        c += __shfl_xor(c, 1);                                              \
        c += __shfl_xor(c, 2);                                              \
        c += __shfl_xor(c, 4);                                              \
        c += __shfl_xor(c, 8);                                              \
        float mn = val ? fmaxf(m, c) : m;                                   \
        float p  = val ? __expf(c - mn) : 0.f;                              \
        float sc = __expf(m - mn);                                          \
        s  = fmaf(s, sc, p);                                                \
        a0 = fmaf(p, Q.x, a0 * sc);                                         \
        a1 = fmaf(p, Q.y, a1 * sc);                                         \
        a2 = fmaf(p, Q.z, a2 * sc);                                         \
        a3 = fmaf(p, Q.w, a3 * sc);                                         \
        m  = mn;                                                            \
    } while (0)

    ONLINE(q0, w);
    ONLINE(q1, w + 4);
    ONLINE(q2, w + 8);
    ONLINE(q3, w + 12);
    ONLINE(q4, w + 16);
    ONLINE(q5, w + 20);
    ONLINE(q6, w + 24);
    ONLINE(q7, w + 28);
    ONLINE(q8, w + 32);
#undef ONLINE

    // publish per-wave state
    *(float4*)&s_acc[w][4 * l] = make_float4(a0, a1, a2, a3);
    s_m[w][l] = m;
    s_s[w][l] = s;
    __syncthreads();

    // ---- merge 4 waves (thread t <-> feature t; holder lane g = t/4) ----
    const int g = t >> 2;
    float m0 = s_m[0][g], m1 = s_m[1][g], m2 = s_m[2][g], m3 = s_m[3][g];
    float M  = fmaxf(fmaxf(m0, m1), fmaxf(m2, m3));
    float w0 = __expf(m0 - M), w1 = __expf(m1 - M);
    float w2 = __expf(m2 - M), w3 = __expf(m3 - M);
    float den = w0 * s_s[0][g] + w1 * s_s[1][g] + w2 * s_s[2][g] + w3 * s_s[3][g];
    float num = w0 * s_acc[0][t] + w1 * s_acc[1][t] + w2 * s_acc[2][t] + w3 * s_acc[3][t];
    float acc = num / den + biasv;

    // ---- LayerNorm over 256 features (two-pass, block reduce) ----
    float ssum = acc;
    #pragma unroll
    for (int off = 32; off; off >>= 1) ssum += __shfl_xor(ssum, off);
    if (l == 0) s_red[w] = ssum;
    __syncthreads();
    float mu = (s_red[0] + s_red[1] + s_red[2] + s_red[3]) * (1.f / 256.f);
    __syncthreads();
    float d  = acc - mu;
    float dv = d * d;
    #pragma unroll
    for (int off = 32; off; off >>= 1) dv += __shfl_xor(dv, off);
    if (l == 0) s_red[w] = dv;
    __syncthreads();
    float var  = (s_red[0] + s_red[1] + s_red[2] + s_red[3]) * (1.f / 256.f);
    float rstd = rsqrtf(var + 1e-5f);
    out[(size_t)node * HD + t] = d * rstd * gv + bv;
}

// ---------------------------------------------------------------------------
extern "C" void kernel_launch(void* const* d_in, const int* in_sizes, int n_in,
                              void* d_out, int out_size, void* d_ws, size_t ws_size,
                              hipStream_t stream)
{
    const float* x     = (const float*)d_in[0];
    const float* adj   = (const float*)d_in[1];
    const float* Wl    = (const float*)d_in[2];
    const float* bl    = (const float*)d_in[3];
    const float* Wr    = (const float*)d_in[4];
    const float* br    = (const float*)d_in[5];
    const float* att   = (const float*)d_in[6];
    const float* bias  = (const float*)d_in[7];
    const float* gamma = (const float*)d_in[8];
    const float* beta  = (const float*)d_in[9];
    float* out = (float*)d_out;

    float* XL = (float*)d_ws;                       // 16 MiB
    float* XR = XL + (size_t)BB * NN * HD;          // 16 MiB

    xlr_kernel<<<BB * NN / 4, 256, 0, stream>>>(x, Wl, bl, Wr, br, XL, XR);
    gat_kernel<<<BB * NN, 256, 0, stream>>>(adj, XL, XR, att, bias, gamma, beta, out);
}